// Round 1
// baseline (190.750 us; speedup 1.0000x reference)
//
#include <hip/hip_runtime.h>

// GAE reverse scan: adv[t] = delta[t] + (gamma*lambda)*adv[t+1]
// delta[t] = reward[t] + gamma*value[t+1] - value[t]
// Exact chunked linear-recurrence decomposition (no truncation):
//   chunk-local suffix scan S_i (zero carry), then adv at chunk start
//   = S_i + c^L * adv(next chunk start).

constexpr int T = 1024;
constexpr int B = 16384;
constexpr int L = 32;        // chunk length (T % L == 0)
constexpr int C = T / L;     // 32 chunks
constexpr float GAMMA = (float)0.99;
constexpr float COEF  = (float)(0.99 * 0.97);   // matches jnp.float32(GAMMA*LAMBDA)

__host__ __device__ constexpr float pow_coef(int n) {
    float p = 1.0f;
    for (int i = 0; i < n; ++i) p *= COEF;
    return p;
}
constexpr float CL = pow_coef(L);   // c^L

// ---------------- Kernel 1: per-chunk local suffix scan -> S ----------------
// thread = (chunk, group of 4 columns). float4 vector loads, coalesced.
__global__ __launch_bounds__(256) void gae_chunk_scan(
    const float* __restrict__ value,   // (T+1, B)
    const float* __restrict__ reward,  // (T, B)
    float* __restrict__ S)             // (C, B) workspace
{
    const int c4    = blockIdx.x * blockDim.x + threadIdx.x;  // column group
    const int chunk = blockIdx.y;
    const int b     = c4 * 4;
    const int t0 = chunk * L;
    const int t1 = t0 + L;

    float4 vnext = *(const float4*)(value + (size_t)t1 * B + b);
    float4 s = make_float4(0.f, 0.f, 0.f, 0.f);

    #pragma unroll 4
    for (int t = t1 - 1; t >= t0; --t) {
        float4 r = *(const float4*)(reward + (size_t)t * B + b);
        float4 v = *(const float4*)(value  + (size_t)t * B + b);
        float dx = r.x + GAMMA * vnext.x - v.x;
        float dy = r.y + GAMMA * vnext.y - v.y;
        float dz = r.z + GAMMA * vnext.z - v.z;
        float dw = r.w + GAMMA * vnext.w - v.w;
        s.x = dx + COEF * s.x;
        s.y = dy + COEF * s.y;
        s.z = dz + COEF * s.z;
        s.w = dw + COEF * s.w;
        vnext = v;
    }
    *(float4*)(S + (size_t)chunk * B + b) = s;
}

// ---------------- Kernel 2: combine carries + emit output ----------------
__global__ __launch_bounds__(256) void gae_emit(
    const float* __restrict__ value,
    const float* __restrict__ reward,
    const float* __restrict__ S,
    float* __restrict__ out)           // (T, B)
{
    const int c4    = blockIdx.x * blockDim.x + threadIdx.x;
    const int chunk = blockIdx.y;
    const int b     = c4 * 4;
    const int t0 = chunk * L;
    const int t1 = t0 + L;

    // carry = adv[t1] = S_{chunk+1} + CL*(S_{chunk+2} + CL*(...))
    float4 carry = make_float4(0.f, 0.f, 0.f, 0.f);
    for (int j = C - 1; j > chunk; --j) {
        float4 sj = *(const float4*)(S + (size_t)j * B + b);
        carry.x = sj.x + CL * carry.x;
        carry.y = sj.y + CL * carry.y;
        carry.z = sj.z + CL * carry.z;
        carry.w = sj.w + CL * carry.w;
    }

    float4 adv = carry;
    float4 vnext = *(const float4*)(value + (size_t)t1 * B + b);

    #pragma unroll 4
    for (int t = t1 - 1; t >= t0; --t) {
        float4 r = *(const float4*)(reward + (size_t)t * B + b);
        float4 v = *(const float4*)(value  + (size_t)t * B + b);
        float dx = r.x + GAMMA * vnext.x - v.x;
        float dy = r.y + GAMMA * vnext.y - v.y;
        float dz = r.z + GAMMA * vnext.z - v.z;
        float dw = r.w + GAMMA * vnext.w - v.w;
        adv.x = dx + COEF * adv.x;
        adv.y = dy + COEF * adv.y;
        adv.z = dz + COEF * adv.z;
        adv.w = dw + COEF * adv.w;
        *(float4*)(out + (size_t)t * B + b) = adv;
        vnext = v;
    }
}

extern "C" void kernel_launch(void* const* d_in, const int* in_sizes, int n_in,
                              void* d_out, int out_size, void* d_ws, size_t ws_size,
                              hipStream_t stream) {
    const float* value  = (const float*)d_in[0];   // (T+1, B)
    const float* reward = (const float*)d_in[1];   // (T, B)
    float* out = (float*)d_out;
    float* S   = (float*)d_ws;                     // needs C*B*4 = 2 MiB

    dim3 block(256);
    dim3 grid(B / 4 / 256, C);   // (16, 32) blocks

    gae_chunk_scan<<<grid, block, 0, stream>>>(value, reward, S);
    gae_emit<<<grid, block, 0, stream>>>(value, reward, S, out);
}